// Round 6
// baseline (3873.826 us; speedup 1.0000x reference)
//
#include <hip/hip_runtime.h>
#include <hip/hip_bf16.h>

#define FD 16

typedef __attribute__((ext_vector_type(2))) float f32x2;
typedef __attribute__((ext_vector_type(4))) float f32x4;
typedef __attribute__((ext_vector_type(4))) unsigned int u32x4;

// ---------------- fp8 e4m3fn encode (RNE, saturating) ----------------
// Stored value represents (orig * 2^15); 2^-15 folded into w1 (exact).
__device__ __forceinline__ unsigned char enc_e4m3(float v) {
  float sv = v * 32768.0f;                    // scale 2^15
  unsigned int bits = __float_as_uint(sv);
  unsigned int s = (bits >> 24) & 0x80u;
  float a = fabsf(sv);
  if (a >= 448.0f) return (unsigned char)(s | 0x7Eu);  // saturate to max finite
  unsigned int tb = __float_as_uint(a * 0x1p-120f);    // fp8 grid == 3-mantissa f32 here
  unsigned int lsb = (tb >> 20) & 1u;
  tb += 0x7FFFFu + lsb;                       // RNE on bottom 20 bits
  unsigned int em = (tb >> 20) & 0x7Fu;
  if (em > 0x7Eu) em = 0x7Eu;
  return (unsigned char)(s | em);
}

// ws layout (byte offsets)
constexpr int SZ0_XT = 2 * 16 * 128 * FD;
constexpr int SZ0_XY = 128 * 128 * FD;
constexpr int SZ1_XT = 2 * 32 * 256 * FD;
constexpr int SZ1_XY = 256 * 256 * FD;
constexpr int SZ2_XT = 2 * 64 * 512 * FD;
constexpr int SZ2_XY = 512 * 512 * FD;
constexpr int OFF0_XT = 0;
constexpr int OFF0_XY = OFF0_XT + SZ0_XT;
constexpr int OFF1_XT = OFF0_XY + SZ0_XY;
constexpr int OFF1_XY = OFF1_XT + SZ1_XT;
constexpr int OFF2_XT = OFF1_XY + SZ1_XY;
constexpr int OFF2_XY = OFF2_XT + SZ2_XT;

// block-range bases for the fused pack kernel (texels/256 per segment)
constexpr int NB0_XT = (2 * 16 * 128) / 256;      // 16
constexpr int NB0_XY = (128 * 128) / 256;         // 64
constexpr int NB1_XT = (2 * 32 * 256) / 256;      // 64
constexpr int NB1_XY = (256 * 256) / 256;         // 256
constexpr int NB2_XT = (2 * 64 * 512) / 256;      // 256
constexpr int NB2_XY = (512 * 512) / 256;         // 1024
constexpr int B0 = 0;
constexpr int B1 = B0 + NB0_XT;    // 16
constexpr int B2 = B1 + NB0_XY;    // 80
constexpr int B3 = B2 + NB1_XT;    // 144
constexpr int B4 = B3 + NB1_XY;    // 400
constexpr int B5 = B4 + NB2_XT;    // 656
constexpr int B6 = B5 + NB2_XY;    // 1680

// ---------------- fused pack: all 6 planes (P,C,H,W) f32 -> (P,H,W,C) fp8 ----
__global__ __launch_bounds__(256) void pack_all_kernel(
    const float* __restrict__ s0, const float* __restrict__ s1,
    const float* __restrict__ s2, const float* __restrict__ s3,
    const float* __restrict__ s4, const float* __restrict__ s5,
    unsigned char* __restrict__ planes)
{
  int bid = blockIdx.x;
  const float* src; int off, H, W, base;
  if      (bid < B1) { src = s0; off = OFF0_XT; H = 16;  W = 128; base = B0; }
  else if (bid < B2) { src = s1; off = OFF0_XY; H = 128; W = 128; base = B1; }
  else if (bid < B3) { src = s2; off = OFF1_XT; H = 32;  W = 256; base = B2; }
  else if (bid < B4) { src = s3; off = OFF1_XY; H = 256; W = 256; base = B3; }
  else if (bid < B5) { src = s4; off = OFF2_XT; H = 64;  W = 512; base = B4; }
  else               { src = s5; off = OFF2_XY; H = 512; W = 512; base = B5; }
  int idx = (bid - base) * 256 + threadIdx.x;   // texel index within (P,H,W)
  int hw  = H * W;
  int w   = idx % W;
  int ph  = idx / W;
  int h   = ph % H;
  int p   = ph / H;
  const float* sp = src + ((size_t)(p * FD) * H + h) * (size_t)W + w;
  unsigned int words[4];
#pragma unroll
  for (int g = 0; g < 4; ++g) {
    unsigned int acc = 0;
#pragma unroll
    for (int c = 0; c < 4; ++c) {
      unsigned int b = enc_e4m3(sp[(size_t)(4 * g + c) * hw]);
      acc |= b << (8 * c);
    }
    words[g] = acc;
  }
  u32x4 v; v.x = words[0]; v.y = words[1]; v.z = words[2]; v.w = words[3];
  *(u32x4*)(planes + off + (size_t)idx * FD) = v;
}

// ---------------- bilinear sample+accumulate (fp8 planes, HW cvt) ----------------
// base -> (H, W, FD) fp8 plane. u -> W axis, v -> H axis, in [-1,1].
template<int H, int W>
__device__ __forceinline__ void sample_add(
    const unsigned char* __restrict__ base, float u, float v, f32x2* __restrict__ f)
{
  float gx = ((u + 1.0f) * 0.5f) * (float)(W - 1);
  float gy = ((v + 1.0f) * 0.5f) * (float)(H - 1);
  float fx0 = floorf(gx), fy0 = floorf(gy);
  float wx = gx - fx0, wy = gy - fy0;
  int x0 = (int)fx0, y0 = (int)fy0;
  int x0c = min(max(x0, 0), W - 1);
  int x1c = min(max(x0 + 1, 0), W - 1);
  int y0c = min(max(y0, 0), H - 1);
  int y1c = min(max(y0 + 1, 0), H - 1);
  // u,v in [-1,1] => out-of-range corners carry exactly-zero weight; clamped
  // reads reproduce zero-padding semantics exactly.
  float w00 = (1.0f - wx) * (1.0f - wy);
  float w01 = wx * (1.0f - wy);
  float w10 = (1.0f - wx) * wy;
  float w11 = wx * wy;
  u32x4 A = *(const u32x4*)(base + ((y0c * W + x0c) << 4));
  u32x4 B = *(const u32x4*)(base + ((y0c * W + x1c) << 4));
  u32x4 C = *(const u32x4*)(base + ((y1c * W + x0c) << 4));
  u32x4 D = *(const u32x4*)(base + ((y1c * W + x1c) << 4));
  f32x2 vw00 = {w00, w00}, vw01 = {w01, w01}, vw10 = {w10, w10}, vw11 = {w11, w11};
#pragma unroll
  for (int g = 0; g < 4; ++g) {
    f32x2 acc0 = f[2 * g + 0];
    f32x2 acc1 = f[2 * g + 1];
    acc0 = __builtin_elementwise_fma(vw00, __builtin_amdgcn_cvt_pk_f32_fp8(A[g], false), acc0);
    acc1 = __builtin_elementwise_fma(vw00, __builtin_amdgcn_cvt_pk_f32_fp8(A[g], true ), acc1);
    acc0 = __builtin_elementwise_fma(vw01, __builtin_amdgcn_cvt_pk_f32_fp8(B[g], false), acc0);
    acc1 = __builtin_elementwise_fma(vw01, __builtin_amdgcn_cvt_pk_f32_fp8(B[g], true ), acc1);
    acc0 = __builtin_elementwise_fma(vw10, __builtin_amdgcn_cvt_pk_f32_fp8(C[g], false), acc0);
    acc1 = __builtin_elementwise_fma(vw10, __builtin_amdgcn_cvt_pk_f32_fp8(C[g], true ), acc1);
    acc0 = __builtin_elementwise_fma(vw11, __builtin_amdgcn_cvt_pk_f32_fp8(D[g], false), acc0);
    acc1 = __builtin_elementwise_fma(vw11, __builtin_amdgcn_cvt_pk_f32_fp8(D[g], true ), acc1);
    f[2 * g + 0] = acc0;
    f[2 * g + 1] = acc1;
  }
}

// 16 rows of layer 1 for TWO points, sharing each weight-row LDS read.
__device__ __forceinline__ void mlp_chunk2(
    const f32x2* __restrict__ fra, const f32x2* __restrict__ frb,
    const float* __restrict__ s_w1, int row0,
    f32x2* __restrict__ h2a, f32x2* __restrict__ h2b)
{
#pragma unroll
  for (int k = 0; k < 16; ++k) {
    float fka = fra[k >> 1][k & 1];
    float fkb = frb[k >> 1][k & 1];
    f32x2 fa2 = {fka, fka};
    f32x2 fb2 = {fkb, fkb};
    const f32x4* wrow = (const f32x4*)(s_w1 + (row0 + k) * 32);
#pragma unroll
    for (int q = 0; q < 8; ++q) {
      f32x4 w4 = wrow[q];
      f32x2 wlo = {w4.x, w4.y};
      f32x2 whi = {w4.z, w4.w};
      h2a[2 * q + 0] = __builtin_elementwise_fma(fa2, wlo, h2a[2 * q + 0]);
      h2a[2 * q + 1] = __builtin_elementwise_fma(fa2, whi, h2a[2 * q + 1]);
      h2b[2 * q + 0] = __builtin_elementwise_fma(fb2, wlo, h2b[2 * q + 0]);
      h2b[2 * q + 1] = __builtin_elementwise_fma(fb2, whi, h2b[2 * q + 1]);
    }
  }
}

// layer2 + sigmoid for one point's h2[16]
__device__ __forceinline__ f32x2 head(
    f32x2* __restrict__ h2, const float* __restrict__ s_w2t, const float* __restrict__ s_b2)
{
  f32x2 zero = {0.0f, 0.0f};
  f32x2 c01 = {0.01f, 0.01f};
  f32x2 oa = zero, ob = zero;
#pragma unroll
  for (int j = 0; j < 16; ++j) {
    f32x2 hp = __builtin_elementwise_max(h2[j], zero);
    f32x2 hn = __builtin_elementwise_min(h2[j], zero);
    f32x2 hj = __builtin_elementwise_fma(c01, hn, hp);
    f32x2 w2a = *(const f32x2*)(s_w2t + 2 * j);
    f32x2 w2b = *(const f32x2*)(s_w2t + 32 + 2 * j);
    oa = __builtin_elementwise_fma(hj, w2a, oa);
    ob = __builtin_elementwise_fma(hj, w2b, ob);
  }
  float o0 = s_b2[0] + oa[0] + oa[1];
  float o1 = s_b2[1] + ob[0] + ob[1];
  f32x2 r;
  r[0] = 1.0f / (1.0f + __expf(-o0));
  r[1] = 1.0f / (1.0f + __expf(-o1));
  return r;
}

// ---------------- main fused kernel: 2 points per thread ----------------
__global__ __launch_bounds__(256) void triplane_kernel(
    const float* __restrict__ coords,
    const unsigned char* __restrict__ planes,
    const float* __restrict__ w1, const float* __restrict__ b1,
    const float* __restrict__ w2, const float* __restrict__ b2,
    float* __restrict__ out, int N)
{
  __shared__ __align__(16) float s_w1[48 * 32];  // pre-scaled by 2^-15 (exact)
  __shared__ float s_b1[32];
  __shared__ float s_w2t[2 * 32];                // transposed: [c][j]
  __shared__ float s_b2[2];
  for (int i = threadIdx.x; i < 48 * 32; i += 256) s_w1[i] = w1[i] * 0x1p-15f;
  if (threadIdx.x < 32) s_b1[threadIdx.x] = b1[threadIdx.x];
  if (threadIdx.x < 64) {
    int j = threadIdx.x >> 1, c = threadIdx.x & 1;
    s_w2t[c * 32 + j] = w2[j * 2 + c];
  }
  if (threadIdx.x < 2)  s_b2[threadIdx.x] = b2[threadIdx.x];
  __syncthreads();

  int gid = blockIdx.x * blockDim.x + threadIdx.x;
  int n0 = 2 * gid;
  if (n0 >= N) return;
  bool hasB = (n0 + 1 < N);
  int n1 = hasB ? (n0 + 1) : n0;

  const float* cpa = coords + 3 * (size_t)n0;
  const float* cpb = coords + 3 * (size_t)n1;
  float xa = cpa[0], ya = cpa[1], ta = cpa[2];
  float xb = cpb[0], yb = cpb[1], tb = cpb[2];

  f32x2 h2a[16], h2b[16];
#pragma unroll
  for (int j = 0; j < 16; ++j) {
    f32x2 b01 = {s_b1[2 * j], s_b1[2 * j + 1]};
    h2a[j] = b01; h2b[j] = b01;
  }

  {  // resolution 0: rt=16, rx=128
    f32x2 fra[8], frb[8];
#pragma unroll
    for (int i = 0; i < 8; ++i) { fra[i] = (f32x2){0.f, 0.f}; frb[i] = (f32x2){0.f, 0.f}; }
    sample_add<16, 128>(planes + OFF0_XT,                 xa, ta, fra);
    sample_add<16, 128>(planes + OFF0_XT,                 xb, tb, frb);
    sample_add<16, 128>(planes + OFF0_XT + 16 * 128 * FD, ya, ta, fra);
    sample_add<16, 128>(planes + OFF0_XT + 16 * 128 * FD, yb, tb, frb);
    sample_add<128, 128>(planes + OFF0_XY,                xa, ya, fra);
    sample_add<128, 128>(planes + OFF0_XY,                xb, yb, frb);
    mlp_chunk2(fra, frb, s_w1, 0, h2a, h2b);
  }
  {  // resolution 1: rt=32, rx=256
    f32x2 fra[8], frb[8];
#pragma unroll
    for (int i = 0; i < 8; ++i) { fra[i] = (f32x2){0.f, 0.f}; frb[i] = (f32x2){0.f, 0.f}; }
    sample_add<32, 256>(planes + OFF1_XT,                 xa, ta, fra);
    sample_add<32, 256>(planes + OFF1_XT,                 xb, tb, frb);
    sample_add<32, 256>(planes + OFF1_XT + 32 * 256 * FD, ya, ta, fra);
    sample_add<32, 256>(planes + OFF1_XT + 32 * 256 * FD, yb, tb, frb);
    sample_add<256, 256>(planes + OFF1_XY,                xa, ya, fra);
    sample_add<256, 256>(planes + OFF1_XY,                xb, yb, frb);
    mlp_chunk2(fra, frb, s_w1, 16, h2a, h2b);
  }
  {  // resolution 2: rt=64, rx=512
    f32x2 fra[8], frb[8];
#pragma unroll
    for (int i = 0; i < 8; ++i) { fra[i] = (f32x2){0.f, 0.f}; frb[i] = (f32x2){0.f, 0.f}; }
    sample_add<64, 512>(planes + OFF2_XT,                 xa, ta, fra);
    sample_add<64, 512>(planes + OFF2_XT,                 xb, tb, frb);
    sample_add<64, 512>(planes + OFF2_XT + 64 * 512 * FD, ya, ta, fra);
    sample_add<64, 512>(planes + OFF2_XT + 64 * 512 * FD, yb, tb, frb);
    sample_add<512, 512>(planes + OFF2_XY,                xa, ya, fra);
    sample_add<512, 512>(planes + OFF2_XY,                xb, yb, frb);
    mlp_chunk2(fra, frb, s_w1, 32, h2a, h2b);
  }

  f32x2 ra = head(h2a, s_w2t, s_b2);
  if (hasB) {
    f32x2 rb = head(h2b, s_w2t, s_b2);
    f32x4 r4; r4.x = ra[0]; r4.y = ra[1]; r4.z = rb[0]; r4.w = rb[1];
    *(f32x4*)(out + 4 * (size_t)gid) = r4;   // 16B-aligned
  } else {
    *(f32x2*)(out + 4 * (size_t)gid) = ra;
  }
}

extern "C" void kernel_launch(void* const* d_in, const int* in_sizes, int n_in,
                              void* d_out, int out_size, void* d_ws, size_t ws_size,
                              hipStream_t stream) {
  const float* coords = (const float*)d_in[0];
  const float* xtyt0  = (const float*)d_in[1];
  const float* xy0    = (const float*)d_in[2];
  const float* xtyt1  = (const float*)d_in[3];
  const float* xy1    = (const float*)d_in[4];
  const float* xtyt2  = (const float*)d_in[5];
  const float* xy2    = (const float*)d_in[6];
  const float* w1     = (const float*)d_in[7];
  const float* b1     = (const float*)d_in[8];
  const float* w2     = (const float*)d_in[9];
  const float* b2     = (const float*)d_in[10];

  unsigned char* planes = (unsigned char*)d_ws;
  const int N = in_sizes[0] / 3;  // 2,000,000

  hipLaunchKernelGGL(pack_all_kernel, dim3(B6), dim3(256), 0, stream,
                     xtyt0, xy0, xtyt1, xy1, xtyt2, xy2, planes);

  int nthreads = (N + 1) / 2;
  int blocks = (nthreads + 255) / 256;
  hipLaunchKernelGGL(triplane_kernel, dim3(blocks), dim3(256), 0, stream,
                     coords, planes, w1, b1, w2, b2, (float*)d_out, N);
}

// Round 7
// 476.950 us; speedup vs baseline: 8.1221x; 8.1221x over previous
//
#include <hip/hip_runtime.h>
#include <hip/hip_bf16.h>

#define FD 16

typedef __attribute__((ext_vector_type(2))) float f32x2;
typedef __attribute__((ext_vector_type(4))) float f32x4;
typedef __attribute__((ext_vector_type(4))) unsigned int u32x4;

// ---------------- fp8 e4m3fn encode (RNE, saturating) ----------------
// Stored value represents (orig * 2^15); 2^-15 folded into w1 (exact).
__device__ __forceinline__ unsigned char enc_e4m3(float v) {
  float sv = v * 32768.0f;
  unsigned int bits = __float_as_uint(sv);
  unsigned int s = (bits >> 24) & 0x80u;
  float a = fabsf(sv);
  if (a >= 448.0f) return (unsigned char)(s | 0x7Eu);
  unsigned int tb = __float_as_uint(a * 0x1p-120f);
  unsigned int lsb = (tb >> 20) & 1u;
  tb += 0x7FFFFu + lsb;
  unsigned int em = (tb >> 20) & 0x7Fu;
  if (em > 0x7Eu) em = 0x7Eu;
  return (unsigned char)(s | em);
}

// ws layout (byte offsets)
constexpr int SZ0_XT = 2 * 16 * 128 * FD;
constexpr int SZ0_XY = 128 * 128 * FD;
constexpr int SZ1_XT = 2 * 32 * 256 * FD;
constexpr int SZ1_XY = 256 * 256 * FD;
constexpr int SZ2_XT = 2 * 64 * 512 * FD;
constexpr int SZ2_XY = 512 * 512 * FD;
constexpr int OFF0_XT = 0;
constexpr int OFF0_XY = OFF0_XT + SZ0_XT;
constexpr int OFF1_XT = OFF0_XY + SZ0_XY;
constexpr int OFF1_XY = OFF1_XT + SZ1_XT;
constexpr int OFF2_XT = OFF1_XY + SZ1_XY;
constexpr int OFF2_XY = OFF2_XT + SZ2_XT;
constexpr size_t PLANES_BYTES = (size_t)OFF2_XY + SZ2_XY;      // 6,881,280

constexpr int NBUCKETS = 1 << 15;                               // 32768
constexpr size_t HIST_OFF = PLANES_BYTES;                       // 4B-aligned
constexpr size_t SORT_OFF = HIST_OFF + (size_t)NBUCKETS * 4;    // 16B-aligned

// block-range bases for the fused pack kernel
constexpr int NB0_XT = (2 * 16 * 128) / 256;
constexpr int NB0_XY = (128 * 128) / 256;
constexpr int NB1_XT = (2 * 32 * 256) / 256;
constexpr int NB1_XY = (256 * 256) / 256;
constexpr int NB2_XT = (2 * 64 * 512) / 256;
constexpr int NB2_XY = (512 * 512) / 256;
constexpr int B0 = 0;
constexpr int B1 = B0 + NB0_XT;
constexpr int B2 = B1 + NB0_XY;
constexpr int B3 = B2 + NB1_XT;
constexpr int B4 = B3 + NB1_XY;
constexpr int B5 = B4 + NB2_XT;
constexpr int B6 = B5 + NB2_XY;   // 1680

// ---------------- fused pack: all 6 planes (P,C,H,W) f32 -> (P,H,W,C) fp8 ----
__global__ __launch_bounds__(256) void pack_all_kernel(
    const float* __restrict__ s0, const float* __restrict__ s1,
    const float* __restrict__ s2, const float* __restrict__ s3,
    const float* __restrict__ s4, const float* __restrict__ s5,
    unsigned char* __restrict__ planes)
{
  int bid = blockIdx.x;
  const float* src; int off, H, W, base;
  if      (bid < B1) { src = s0; off = OFF0_XT; H = 16;  W = 128; base = B0; }
  else if (bid < B2) { src = s1; off = OFF0_XY; H = 128; W = 128; base = B1; }
  else if (bid < B3) { src = s2; off = OFF1_XT; H = 32;  W = 256; base = B2; }
  else if (bid < B4) { src = s3; off = OFF1_XY; H = 256; W = 256; base = B3; }
  else if (bid < B5) { src = s4; off = OFF2_XT; H = 64;  W = 512; base = B4; }
  else               { src = s5; off = OFF2_XY; H = 512; W = 512; base = B5; }
  int idx = (bid - base) * 256 + threadIdx.x;
  int hw  = H * W;
  int w   = idx % W;
  int ph  = idx / W;
  int h   = ph % H;
  int p   = ph / H;
  const float* sp = src + ((size_t)(p * FD) * H + h) * (size_t)W + w;
  unsigned int words[4];
#pragma unroll
  for (int g = 0; g < 4; ++g) {
    unsigned int acc = 0;
#pragma unroll
    for (int c = 0; c < 4; ++c) {
      unsigned int b = enc_e4m3(sp[(size_t)(4 * g + c) * hw]);
      acc |= b << (8 * c);
    }
    words[g] = acc;
  }
  u32x4 v; v.x = words[0]; v.y = words[1]; v.z = words[2]; v.w = words[3];
  *(u32x4*)(planes + off + (size_t)idx * FD) = v;
}

// ---------------- spatial bucketing ----------------
__device__ __forceinline__ int bucket_key(float x, float y, float t) {
  int qx = min(63, max(0, (int)((x + 1.0f) * 32.0f)));
  int qy = min(63, max(0, (int)((y + 1.0f) * 32.0f)));
  int qt = min(7,  max(0, (int)((t + 1.0f) * 4.0f)));
  return (qt << 12) | (qy << 6) | qx;
}

__global__ __launch_bounds__(256) void hist_kernel(
    const float* __restrict__ coords, unsigned int* __restrict__ hist, int N)
{
  int n = blockIdx.x * blockDim.x + threadIdx.x;
  if (n >= N) return;
  const float* c = coords + 3 * (size_t)n;
  atomicAdd(&hist[bucket_key(c[0], c[1], c[2])], 1u);
}

__global__ __launch_bounds__(1024) void scan_kernel(unsigned int* __restrict__ hist)
{
  __shared__ unsigned int s[1024];
  int tid = threadIdx.x;
  int base = tid * 32;
  unsigned int loc[32];
  unsigned int sum = 0;
#pragma unroll
  for (int i = 0; i < 32; ++i) { loc[i] = hist[base + i]; sum += loc[i]; }
  s[tid] = sum;
  __syncthreads();
  for (int off = 1; off < 1024; off <<= 1) {
    unsigned int v = 0;
    if (tid >= off) v = s[tid - off];
    __syncthreads();
    s[tid] += v;
    __syncthreads();
  }
  unsigned int run = (tid > 0) ? s[tid - 1] : 0u;   // exclusive prefix
#pragma unroll
  for (int i = 0; i < 32; ++i) { unsigned int c = loc[i]; hist[base + i] = run; run += c; }
}

__global__ __launch_bounds__(256) void scatter_kernel(
    const float* __restrict__ coords, unsigned int* __restrict__ hist,
    float* __restrict__ sorted, int N)
{
  int n = blockIdx.x * blockDim.x + threadIdx.x;
  if (n >= N) return;
  const float* c = coords + 3 * (size_t)n;
  float x = c[0], y = c[1], t = c[2];
  unsigned int pos = atomicAdd(&hist[bucket_key(x, y, t)], 1u);
  f32x4 v; v.x = x; v.y = y; v.z = t; v.w = __uint_as_float((unsigned int)n);
  *(f32x4*)(sorted + 4 * (size_t)pos) = v;
}

// ---------------- bilinear sample+accumulate (fp8 planes, HW cvt) ----------------
template<int H, int W>
__device__ __forceinline__ void sample_add(
    const unsigned char* __restrict__ base, float u, float v, f32x2* __restrict__ f)
{
  float gx = ((u + 1.0f) * 0.5f) * (float)(W - 1);
  float gy = ((v + 1.0f) * 0.5f) * (float)(H - 1);
  float fx0 = floorf(gx), fy0 = floorf(gy);
  float wx = gx - fx0, wy = gy - fy0;
  int x0 = (int)fx0, y0 = (int)fy0;
  int x0c = min(max(x0, 0), W - 1);
  int x1c = min(max(x0 + 1, 0), W - 1);
  int y0c = min(max(y0, 0), H - 1);
  int y1c = min(max(y0 + 1, 0), H - 1);
  // u,v in [-1,1] => out-of-range corners carry exactly-zero weight; clamped
  // reads reproduce zero-padding semantics exactly.
  float w00 = (1.0f - wx) * (1.0f - wy);
  float w01 = wx * (1.0f - wy);
  float w10 = (1.0f - wx) * wy;
  float w11 = wx * wy;
  u32x4 A = *(const u32x4*)(base + ((y0c * W + x0c) << 4));
  u32x4 B = *(const u32x4*)(base + ((y0c * W + x1c) << 4));
  u32x4 C = *(const u32x4*)(base + ((y1c * W + x0c) << 4));
  u32x4 D = *(const u32x4*)(base + ((y1c * W + x1c) << 4));
  f32x2 vw00 = {w00, w00}, vw01 = {w01, w01}, vw10 = {w10, w10}, vw11 = {w11, w11};
#pragma unroll
  for (int g = 0; g < 4; ++g) {
    f32x2 acc0 = f[2 * g + 0];
    f32x2 acc1 = f[2 * g + 1];
    acc0 = __builtin_elementwise_fma(vw00, __builtin_amdgcn_cvt_pk_f32_fp8(A[g], false), acc0);
    acc1 = __builtin_elementwise_fma(vw00, __builtin_amdgcn_cvt_pk_f32_fp8(A[g], true ), acc1);
    acc0 = __builtin_elementwise_fma(vw01, __builtin_amdgcn_cvt_pk_f32_fp8(B[g], false), acc0);
    acc1 = __builtin_elementwise_fma(vw01, __builtin_amdgcn_cvt_pk_f32_fp8(B[g], true ), acc1);
    acc0 = __builtin_elementwise_fma(vw10, __builtin_amdgcn_cvt_pk_f32_fp8(C[g], false), acc0);
    acc1 = __builtin_elementwise_fma(vw10, __builtin_amdgcn_cvt_pk_f32_fp8(C[g], true ), acc1);
    acc0 = __builtin_elementwise_fma(vw11, __builtin_amdgcn_cvt_pk_f32_fp8(D[g], false), acc0);
    acc1 = __builtin_elementwise_fma(vw11, __builtin_amdgcn_cvt_pk_f32_fp8(D[g], true ), acc1);
    f[2 * g + 0] = acc0;
    f[2 * g + 1] = acc1;
  }
}

__device__ __forceinline__ void mlp_chunk(
    const f32x2* __restrict__ fr, const float* __restrict__ s_w1, int row0,
    f32x2* __restrict__ h2)
{
#pragma unroll
  for (int k = 0; k < 16; ++k) {
    float fk = fr[k >> 1][k & 1];
    f32x2 fk2 = {fk, fk};
    const f32x4* wrow = (const f32x4*)(s_w1 + (row0 + k) * 32);
#pragma unroll
    for (int q = 0; q < 8; ++q) {
      f32x4 w4 = wrow[q];
      f32x2 wlo = {w4.x, w4.y};
      f32x2 whi = {w4.z, w4.w};
      h2[2 * q + 0] = __builtin_elementwise_fma(fk2, wlo, h2[2 * q + 0]);
      h2[2 * q + 1] = __builtin_elementwise_fma(fk2, whi, h2[2 * q + 1]);
    }
  }
}

// full per-point body; writes result to out[2*outIdx]
__device__ __forceinline__ void triplane_point(
    float x, float y, float t,
    const unsigned char* __restrict__ planes,
    const float* __restrict__ s_w1, const float* __restrict__ s_b1,
    const float* __restrict__ s_w2t, const float* __restrict__ s_b2,
    float* __restrict__ out, size_t outIdx)
{
  f32x2 h2[16];
#pragma unroll
  for (int j = 0; j < 16; ++j) { h2[j][0] = s_b1[2 * j]; h2[j][1] = s_b1[2 * j + 1]; }

  {
    f32x2 fr[8];
#pragma unroll
    for (int i = 0; i < 8; ++i) fr[i] = (f32x2){0.f, 0.f};
    sample_add<16, 128>(planes + OFF0_XT,                 x, t, fr);
    sample_add<16, 128>(planes + OFF0_XT + 16 * 128 * FD, y, t, fr);
    sample_add<128, 128>(planes + OFF0_XY,                x, y, fr);
    mlp_chunk(fr, s_w1, 0, h2);
  }
  {
    f32x2 fr[8];
#pragma unroll
    for (int i = 0; i < 8; ++i) fr[i] = (f32x2){0.f, 0.f};
    sample_add<32, 256>(planes + OFF1_XT,                 x, t, fr);
    sample_add<32, 256>(planes + OFF1_XT + 32 * 256 * FD, y, t, fr);
    sample_add<256, 256>(planes + OFF1_XY,                x, y, fr);
    mlp_chunk(fr, s_w1, 16, h2);
  }
  {
    f32x2 fr[8];
#pragma unroll
    for (int i = 0; i < 8; ++i) fr[i] = (f32x2){0.f, 0.f};
    sample_add<64, 512>(planes + OFF2_XT,                 x, t, fr);
    sample_add<64, 512>(planes + OFF2_XT + 64 * 512 * FD, y, t, fr);
    sample_add<512, 512>(planes + OFF2_XY,                x, y, fr);
    mlp_chunk(fr, s_w1, 32, h2);
  }

  f32x2 zero = {0.0f, 0.0f};
  f32x2 c01 = {0.01f, 0.01f};
  f32x2 oa = zero, ob = zero;
#pragma unroll
  for (int j = 0; j < 16; ++j) {
    f32x2 hp = __builtin_elementwise_max(h2[j], zero);
    f32x2 hn = __builtin_elementwise_min(h2[j], zero);
    f32x2 hj = __builtin_elementwise_fma(c01, hn, hp);
    f32x2 w2a = *(const f32x2*)(s_w2t + 2 * j);
    f32x2 w2b = *(const f32x2*)(s_w2t + 32 + 2 * j);
    oa = __builtin_elementwise_fma(hj, w2a, oa);
    ob = __builtin_elementwise_fma(hj, w2b, ob);
  }
  float o0 = s_b2[0] + oa[0] + oa[1];
  float o1 = s_b2[1] + ob[0] + ob[1];
  f32x2 r;
  r[0] = 1.0f / (1.0f + __expf(-o0));
  r[1] = 1.0f / (1.0f + __expf(-o1));
  *(f32x2*)(out + 2 * outIdx) = r;
}

#define LOAD_WEIGHTS                                                          \
  __shared__ __align__(16) float s_w1[48 * 32];                               \
  __shared__ float s_b1[32];                                                  \
  __shared__ float s_w2t[2 * 32];                                             \
  __shared__ float s_b2[2];                                                   \
  for (int i = threadIdx.x; i < 48 * 32; i += 256) s_w1[i] = w1[i] * 0x1p-15f;\
  if (threadIdx.x < 32) s_b1[threadIdx.x] = b1[threadIdx.x];                  \
  if (threadIdx.x < 64) {                                                     \
    int j = threadIdx.x >> 1, c = threadIdx.x & 1;                            \
    s_w2t[c * 32 + j] = w2[j * 2 + c];                                        \
  }                                                                           \
  if (threadIdx.x < 2) s_b2[threadIdx.x] = b2[threadIdx.x];                   \
  __syncthreads();

// sorted path: coalesced float4 {x,y,t,idx} reads, scattered 8B output store
__global__ __launch_bounds__(256) void triplane_sorted_kernel(
    const float* __restrict__ sorted,
    const unsigned char* __restrict__ planes,
    const float* __restrict__ w1, const float* __restrict__ b1,
    const float* __restrict__ w2, const float* __restrict__ b2,
    float* __restrict__ out, int N)
{
  LOAD_WEIGHTS
  int n = blockIdx.x * blockDim.x + threadIdx.x;
  if (n >= N) return;
  f32x4 c = *(const f32x4*)(sorted + 4 * (size_t)n);
  unsigned int orig = __float_as_uint(c.w);
  triplane_point(c.x, c.y, c.z, planes, s_w1, s_b1, s_w2t, s_b2, out, (size_t)orig);
}

// fallback path (ws too small for sort buffers): direct coords order
__global__ __launch_bounds__(256) void triplane_direct_kernel(
    const float* __restrict__ coords,
    const unsigned char* __restrict__ planes,
    const float* __restrict__ w1, const float* __restrict__ b1,
    const float* __restrict__ w2, const float* __restrict__ b2,
    float* __restrict__ out, int N)
{
  LOAD_WEIGHTS
  int n = blockIdx.x * blockDim.x + threadIdx.x;
  if (n >= N) return;
  const float* cp = coords + 3 * (size_t)n;
  triplane_point(cp[0], cp[1], cp[2], planes, s_w1, s_b1, s_w2t, s_b2, out, (size_t)n);
}

extern "C" void kernel_launch(void* const* d_in, const int* in_sizes, int n_in,
                              void* d_out, int out_size, void* d_ws, size_t ws_size,
                              hipStream_t stream) {
  const float* coords = (const float*)d_in[0];
  const float* xtyt0  = (const float*)d_in[1];
  const float* xy0    = (const float*)d_in[2];
  const float* xtyt1  = (const float*)d_in[3];
  const float* xy1    = (const float*)d_in[4];
  const float* xtyt2  = (const float*)d_in[5];
  const float* xy2    = (const float*)d_in[6];
  const float* w1     = (const float*)d_in[7];
  const float* b1     = (const float*)d_in[8];
  const float* w2     = (const float*)d_in[9];
  const float* b2     = (const float*)d_in[10];

  unsigned char* ws = (unsigned char*)d_ws;
  unsigned char* planes = ws;
  const int N = in_sizes[0] / 3;  // 2,000,000

  hipLaunchKernelGGL(pack_all_kernel, dim3(B6), dim3(256), 0, stream,
                     xtyt0, xy0, xtyt1, xy1, xtyt2, xy2, planes);

  const size_t needed = SORT_OFF + (size_t)N * 16;
  const int pblocks = (N + 255) / 256;

  if (ws_size >= needed) {
    unsigned int* hist = (unsigned int*)(ws + HIST_OFF);
    float* sorted = (float*)(ws + SORT_OFF);
    hipMemsetAsync(hist, 0, (size_t)NBUCKETS * 4, stream);
    hipLaunchKernelGGL(hist_kernel, dim3(pblocks), dim3(256), 0, stream,
                       coords, hist, N);
    hipLaunchKernelGGL(scan_kernel, dim3(1), dim3(1024), 0, stream, hist);
    hipLaunchKernelGGL(scatter_kernel, dim3(pblocks), dim3(256), 0, stream,
                       coords, hist, sorted, N);
    hipLaunchKernelGGL(triplane_sorted_kernel, dim3(pblocks), dim3(256), 0, stream,
                       sorted, planes, w1, b1, w2, b2, (float*)d_out, N);
  } else {
    hipLaunchKernelGGL(triplane_direct_kernel, dim3(pblocks), dim3(256), 0, stream,
                       coords, planes, w1, b1, w2, b2, (float*)d_out, N);
  }
}